// Round 5
// baseline (1396.478 us; speedup 1.0000x reference)
//
#include <hip/hip_runtime.h>
#include <hip/hip_bf16.h>
#include <stdint.h>

typedef __hip_bfloat16 bf16;
typedef __attribute__((ext_vector_type(8))) short short8;   // 8 bf16 (4 VGPRs)
typedef __attribute__((ext_vector_type(4))) float floatx4;  // 4 fp32 acc

#define Bb 4
#define Nn 4096
#define Ww 1024
#define Hh 16
#define Aa 64
#define Pp 64
#define Jj 64   // scan chunks per (b,h)
#define Ll 64   // chunk length

__device__ __forceinline__ float clamp20(float z){ return fminf(fmaxf(z, -20.0f), 20.0f); }

__device__ __forceinline__ void gl_lds16(const bf16* g, bf16* l){
    __builtin_amdgcn_global_load_lds((const __attribute__((address_space(1))) void*)g,
                                     (__attribute__((address_space(3))) void*)l, 16, 0, 0);
}

// ===== prep megakernel: cvt_x | t_vw+t_ow | t_k | p_kernel | zero sync ====
// blocks [0,16384)      : x fp32 -> bf16 (4 elems/thread)
// blocks [16384,20480)  : VWt + OWt transposes (1M elems)
// blocks [20480,20736)  : Ktp build (64K elems)
// blocks [20736,20992)  : p1 / p2e sinusoid tables
// blocks [20992,21009)  : zero ticket+flags (4097 ints)
__global__ __launch_bounds__(256) void prep_all(
    const float* __restrict__ x,
    const float* __restrict__ k1, const float* __restrict__ k2, const float* __restrict__ k3,
    const float* __restrict__ a1, const float* __restrict__ a2,
    const float* __restrict__ b1, const float* __restrict__ b2, const float* __restrict__ c,
    const float* __restrict__ vw, const float* __restrict__ ow,
    bf16* __restrict__ xb, bf16* __restrict__ Ktp,
    bf16* __restrict__ VWt, bf16* __restrict__ OWt,
    float* __restrict__ p1, float* __restrict__ p2e,
    int* __restrict__ sync_buf){
    const int blk = blockIdx.x, tid = threadIdx.x;
    if (blk < 16384){
        size_t i = ((size_t)blk * 256 + tid) * 4;
        float4 v = *(const float4*)(x + i);
        bf16 t0 = __float2bfloat16(v.x), t1 = __float2bfloat16(v.y);
        bf16 t2 = __float2bfloat16(v.z), t3 = __float2bfloat16(v.w);
        ushort4 pk = make_ushort4(*(unsigned short*)&t0, *(unsigned short*)&t1,
                                  *(unsigned short*)&t2, *(unsigned short*)&t3);
        *(ushort4*)(xb + i) = pk;
    } else if (blk < 20480){
        int idx = (blk - 16384) * 256 + tid;        // 0..1M
        {   // VWt[r*1024 + w] = vw[h,w,a], r = h*64+a
            int r = idx >> 10, w = idx & 1023;
            int h = r >> 6, a = r & 63;
            VWt[idx] = __float2bfloat16(vw[(h << 16) + (w << 6) + a]);
        }
        {   // OWt[w*1024 + r] = ow[h,w,a]
            int w = idx >> 10, r = idx & 1023;
            int h = r >> 6, a = r & 63;
            OWt[idx] = __float2bfloat16(ow[(h << 16) + (w << 6) + a]);
        }
    } else if (blk < 20736){
        int idx = (blk - 20480) * 256 + tid;        // r*1024 + k
        int r = idx >> 10, k = idx & 1023;
        float v = 0.f;
        if (r < 16)      v = k1[r * 1024 + k];
        else if (r < 32) v = k2[(r - 16) * 1024 + k];
        else if (r < 48) v = k3[(r - 32) * 1024 + k];
        Ktp[idx] = __float2bfloat16(v);
    } else if (blk < 20992){
        int idx = (blk - 20736) * 256 + tid;        // h*N + i
        int h = idx >> 12, i = idx & (Nn - 1);
        float t = (float)i * (1.0f / (float)(Nn - 1));
        float s1 = 0.f, s2 = 0.f;
        for (int p = 0; p < Pp; ++p){
            float av1 = a1[h * Pp + p], av2 = a2[h * Pp + p];
            float bv1 = b1[h * Pp + p], bv2 = b2[h * Pp + p];
            float cv  = c [h * Pp + p];
            s1 += __sinf(av1 * t + bv1) * cv;
            s2 += __sinf(av2 * t + bv2) * cv;
        }
        p1[idx]  = s1;
        p2e[idx] = expf(clamp20(s2));
    } else {
        int idx = (blk - 20992) * 256 + tid;
        if (idx < 4097) sync_buf[idx] = 0;
    }
}

// ---- projection GEMM: S[16384,48] = xb * Ktp^T, epilogue exp+scatter -----
__global__ __launch_bounds__(256) void proj_gemm(const bf16* __restrict__ A,
                                                 const bf16* __restrict__ Ktp,
                                                 const float* __restrict__ p1,
                                                 float* __restrict__ cross_e,
                                                 float* __restrict__ diag_e,
                                                 float* __restrict__ extra_e){
    __shared__ bf16 As[256 * 32];
    __shared__ bf16 Bs[64 * 32];
    const int tid  = threadIdx.x;
    const int wave = tid >> 6, lane = tid & 63;
    const int m0 = blockIdx.x * 256;

    const int lrow = lane >> 2;            // 0..15
    const int scol = (lane & 3) * 8;       // 0,8,16,24
    const bf16* Bg = Ktp + (size_t)(wave * 16 + lrow) * 1024 + scol;
    bf16* Bl = Bs + (wave * 16) * 32;

    floatx4 acc[4][3] = {};
    const int fr = lane & 15;
    const int fk = (lane >> 4) * 8;

    for (int k0 = 0; k0 < 1024; k0 += 32){
#pragma unroll
        for (int q = 0; q < 4; ++q){
            int srow = wave * 64 + q * 16 + lrow;
            gl_lds16(A + (size_t)(m0 + srow) * 1024 + k0 + scol, As + (wave * 64 + q * 16) * 32);
        }
        gl_lds16(Bg + k0, Bl);
        __syncthreads();
        short8 af[4], bfr[3];
#pragma unroll
        for (int i = 0; i < 4; ++i)
            af[i] = *(const short8*)&As[(wave * 64 + i * 16 + fr) * 32 + fk];
#pragma unroll
        for (int j = 0; j < 3; ++j)
            bfr[j] = *(const short8*)&Bs[(j * 16 + fr) * 32 + fk];
#pragma unroll
        for (int i = 0; i < 4; ++i)
#pragma unroll
            for (int j = 0; j < 3; ++j)
                acc[i][j] = __builtin_amdgcn_mfma_f32_16x16x32_bf16(af[i], bfr[j], acc[i][j], 0, 0, 0);
        __syncthreads();
    }

    const int cr = (lane >> 4) * 4;
#pragma unroll
    for (int i = 0; i < 4; ++i){
#pragma unroll
        for (int j = 0; j < 3; ++j){
            float* dst = (j == 0) ? cross_e : (j == 1) ? diag_e : extra_e;
#pragma unroll
            for (int r = 0; r < 4; ++r){
                int row = m0 + wave * 64 + i * 16 + cr + r;
                int n = row & (Nn - 1), b = row >> 12;
                float s = acc[i][j][r];
                if (j == 0) s += p1[fr * Nn + n];
                dst[(b * Hh + fr) * Nn + n] = expf(clamp20(s));
            }
        }
    }
}

// ---- MFMA GEMM, BK=64, XOR-swizzled LDS: C[M,N] = A[M,K]*Bt[N,K]^T -------
// 128x128 tile, 4 waves (2x2), 32 MFMAs per barrier-pair.
template<int WRITE_BF16>
__global__ __launch_bounds__(256) void gemm_bt(const bf16* __restrict__ A,
                                               const bf16* __restrict__ Bt,
                                               void* __restrict__ Cv,
                                               int M, int N, int K){
    __shared__ bf16 As[128 * 64];
    __shared__ bf16 Bs[128 * 64];
    const int tid  = threadIdx.x;
    const int wave = tid >> 6, lane = tid & 63;
    const int m0 = blockIdx.y * 128, n0 = blockIdx.x * 128;
    const int wm = (wave & 1) * 64, wn = (wave >> 1) * 64;

    // staging: wave stages rows [wave*32, wave*32+32), 8 rows per call.
    // source column XOR-swizzled so LDS chunk c at row r holds logical chunk c^(r&7).
    const int lrow = lane >> 3;                          // 0..7
    const int lcol = ((lane & 7) ^ lrow) * 8;            // swizzled source col
    const bf16* Ag = A  + (size_t)(m0 + wave * 32 + lrow) * K + lcol;
    const bf16* Bg = Bt + (size_t)(n0 + wave * 32 + lrow) * K + lcol;
    bf16* Al = As + (wave * 32) * 64;
    bf16* Bl = Bs + (wave * 32) * 64;

    floatx4 acc[4][4] = {};
    const int fr = lane & 15;
    const int quad = lane >> 4;

    for (int k0 = 0; k0 < K; k0 += 64){
#pragma unroll
        for (int q = 0; q < 4; ++q){
            gl_lds16(Ag + k0 + (size_t)(q * 8) * K, Al + q * 8 * 64);
            gl_lds16(Bg + k0 + (size_t)(q * 8) * K, Bl + q * 8 * 64);
        }
        __syncthreads();
#pragma unroll
        for (int kk = 0; kk < 64; kk += 32){
            const int lbase = (kk >> 3) + quad;          // logical 8-elem chunk
            short8 af[4], bfr[4];
#pragma unroll
            for (int i = 0; i < 4; ++i){
                int R = wm + i * 16 + fr;
                af[i] = *(const short8*)&As[R * 64 + ((lbase ^ (R & 7)) << 3)];
            }
#pragma unroll
            for (int j = 0; j < 4; ++j){
                int R = wn + j * 16 + fr;
                bfr[j] = *(const short8*)&Bs[R * 64 + ((lbase ^ (R & 7)) << 3)];
            }
#pragma unroll
            for (int i = 0; i < 4; ++i)
#pragma unroll
                for (int j = 0; j < 4; ++j)
                    acc[i][j] = __builtin_amdgcn_mfma_f32_16x16x32_bf16(af[i], bfr[j], acc[i][j], 0, 0, 0);
        }
        __syncthreads();
    }

    // C/D layout: col = lane&15, row = quad*4 + reg  [m89/m91 verified]
    const int cr = quad * 4;
#pragma unroll
    for (int i = 0; i < 4; ++i)
#pragma unroll
        for (int j = 0; j < 4; ++j){
            int row = m0 + wm + i * 16 + cr;
            int col = n0 + wn + j * 16 + fr;
            if (WRITE_BF16){
                bf16* C = (bf16*)Cv;
#pragma unroll
                for (int r = 0; r < 4; ++r)
                    C[(size_t)(row + r) * N + col] = __float2bfloat16(acc[i][j][r]);
            } else {
                float* C = (float*)Cv;
#pragma unroll
                for (int r = 0; r < 4; ++r)
                    C[(size_t)(row + r) * N + col] = acc[i][j][r];
            }
        }
}

// ---- fused scan: ticket-ordered decoupled lookback, single pass ----------
// one 64-lane block per chunk; lane = a. All cross-block comm via
// device-scope atomics (XCD L2s are not coherent for plain loads).
__global__ __launch_bounds__(64) void scan_fused(
    const bf16* __restrict__ values,
    const float* __restrict__ cross_e, const float* __restrict__ diag_e,
    const float* __restrict__ extra_e, const float* __restrict__ p2e,
    int* sync_buf,          // [0]=ticket, [1..4096]=flags (0 none /1 agg /2 prefix)
    float* agg_c, float* agg_cv, float* pre_c, float* pre_cv,
    bf16* __restrict__ out2){
    const int lane = threadIdx.x;
    int* ticket = sync_buf;
    int* flags  = sync_buf + 1;

    int tk = 0;
    if (lane == 0) tk = atomicAdd(ticket, 1);
    tk = __shfl(tk, 0);
    const int g = tk;
    const int j = g & (Jj - 1), bh = g >> 6;
    const int h = bh & (Hh - 1), b = bh >> 4;

    const float* cp = cross_e + bh * Nn + j * Ll;
    const bf16* vbase = values + ((size_t)(b * Nn + j * Ll) << 10) + (h << 6) + lane;

    // sweep 1: local sums
    float sc = 0.f, scv = 0.f;
    for (int t = 0; t < Ll; ++t){
        float ce = cp[t];
        float v = __bfloat162float(vbase[(size_t)t << 10]);
        sc += ce;
        scv += ce * v;
    }

    // publish aggregate (j>0 only; j==0 publishes prefix directly)
    if (j > 0){
        atomicExch(&agg_cv[(g << 6) + lane], scv);
        if (lane == 0) atomicExch(&agg_c[g], sc);
        __threadfence();
        if (lane == 0) atomicExch(&flags[g], 1);
    }

    // lookback for exclusive prefix
    float pc = 0.f, pcv = 0.f;
    if (j > 0){
        int p = g - 1;
        while (true){
            int f = 0;
            if (lane == 0){
                do { f = atomicAdd(&flags[p], 0); } while (f == 0);
            }
            f = __shfl(f, 0);
            __threadfence();
            if (f == 2){
                pcv += atomicAdd(&pre_cv[(p << 6) + lane], 0.0f);
                if (lane == 0) pc += atomicAdd(&pre_c[p], 0.0f);
                break;
            } else {
                pcv += atomicAdd(&agg_cv[(p << 6) + lane], 0.0f);
                if (lane == 0) pc += atomicAdd(&agg_c[p], 0.0f);
                --p;   // terminates at domain's j==0 (flag 2), never crosses domain
            }
        }
        pc = __shfl(pc, 0);
    }

    // publish inclusive prefix
    atomicExch(&pre_cv[(g << 6) + lane], pcv + scv);
    if (lane == 0) atomicExch(&pre_c[g], pc + sc);
    __threadfence();
    if (lane == 0) atomicExch(&flags[g], 2);

    // sweep 2: apply + pointwise
    const float* dp = diag_e  + bh * Nn + j * Ll;
    const float* ep = extra_e + bh * Nn + j * Ll;
    const float* pp = p2e + h * Nn + j * Ll;
    bf16* obase = out2 + ((size_t)(b * Nn + j * Ll) << 10) + (h << 6) + lane;
    float rc = pc, rcv = pcv;
    for (int t = 0; t < Ll; ++t){
        float ce = cp[t], de = dp[t], ee = ep[t], pe = pp[t];
        float v = __bfloat162float(vbase[(size_t)t << 10]);
        rcv += ce * v;
        rc  += ce;
        float pee = pe * ee;
        obase[(size_t)t << 10] = __float2bfloat16((rcv * pee + v * de) / (rc * pee + de));
    }
}

extern "C" void kernel_launch(void* const* d_in, const int* in_sizes, int n_in,
                              void* d_out, int out_size, void* d_ws, size_t ws_size,
                              hipStream_t stream){
    const float* x  = (const float*)d_in[0];
    const float* k1 = (const float*)d_in[1];
    const float* k2 = (const float*)d_in[2];
    const float* k3 = (const float*)d_in[3];
    const float* a1 = (const float*)d_in[4];
    const float* a2 = (const float*)d_in[5];
    const float* b1 = (const float*)d_in[6];
    const float* b2 = (const float*)d_in[7];
    const float* c  = (const float*)d_in[8];
    const float* vw = (const float*)d_in[9];
    const float* ow = (const float*)d_in[10];
    float* out = (float*)d_out;

    char* p = (char*)d_ws;
    auto alloc = [&](size_t bytes) -> void* {
        void* r = (void*)p;
        p += (bytes + 255) & ~(size_t)255;
        return r;
    };
    bf16*  xb      = (bf16*) alloc((size_t)Bb * Nn * Ww * 2);
    bf16*  Ktp     = (bf16*) alloc((size_t)64 * Ww * 2);
    bf16*  VWt     = (bf16*) alloc((size_t)Hh * Aa * Ww * 2);
    bf16*  OWt     = (bf16*) alloc((size_t)Ww * Hh * Aa * 2);
    float* p1      = (float*)alloc((size_t)Hh * Nn * 4);
    float* p2e     = (float*)alloc((size_t)Hh * Nn * 4);
    float* cross_e = (float*)alloc((size_t)Bb * Hh * Nn * 4);
    float* diag_e  = (float*)alloc((size_t)Bb * Hh * Nn * 4);
    float* extra_e = (float*)alloc((size_t)Bb * Hh * Nn * 4);
    int*   syncb   = (int*)  alloc((size_t)4097 * 4);
    float* agg_c   = (float*)alloc((size_t)4096 * 4);
    float* pre_c   = (float*)alloc((size_t)4096 * 4);
    float* agg_cv  = (float*)alloc((size_t)4096 * 64 * 4);
    float* pre_cv  = (float*)alloc((size_t)4096 * 64 * 4);
    bf16*  values  = (bf16*) alloc((size_t)Bb * Nn * Hh * Aa * 2);
    bf16*  out2    = (bf16*) alloc((size_t)Bb * Nn * Hh * Aa * 2);

    prep_all<<<21009, 256, 0, stream>>>(x, k1, k2, k3, a1, a2, b1, b2, c, vw, ow,
                                        xb, Ktp, VWt, OWt, p1, p2e, syncb);
    proj_gemm<<<(Bb * Nn) / 256, 256, 0, stream>>>(xb, Ktp, p1, cross_e, diag_e, extra_e);
    gemm_bt<1><<<dim3((Hh * Aa) / 128, (Bb * Nn) / 128), 256, 0, stream>>>(xb, VWt, (void*)values, Bb * Nn, Hh * Aa, Ww);
    scan_fused<<<Bb * Hh * Jj, 64, 0, stream>>>(values, cross_e, diag_e, extra_e, p2e,
                                                syncb, agg_c, agg_cv, pre_c, pre_cv, out2);
    gemm_bt<0><<<dim3(Ww / 128, (Bb * Nn) / 128), 256, 0, stream>>>(out2, OWt, (void*)out, Bb * Nn, Ww, Hh * Aa);
}

// Round 6
// 327.783 us; speedup vs baseline: 4.2604x; 4.2604x over previous
//
#include <hip/hip_runtime.h>
#include <hip/hip_bf16.h>
#include <stdint.h>

typedef __hip_bfloat16 bf16;
typedef __attribute__((ext_vector_type(8))) short short8;   // 8 bf16 (4 VGPRs)
typedef __attribute__((ext_vector_type(4))) float floatx4;  // 4 fp32 acc

#define Bb 4
#define Nn 4096
#define Ww 1024
#define Hh 16
#define Aa 64
#define Pp 64
#define Jj 64   // scan chunks per (b,h)
#define Ll 64   // chunk length

__device__ __forceinline__ float clamp20(float z){ return fminf(fmaxf(z, -20.0f), 20.0f); }

__device__ __forceinline__ void gl_lds16(const bf16* g, bf16* l){
    __builtin_amdgcn_global_load_lds((const __attribute__((address_space(1))) void*)g,
                                     (__attribute__((address_space(3))) void*)l, 16, 0, 0);
}

// ===== prep megakernel: cvt_x | t_vw+t_ow | t_k | p_kernel ================
// blocks [0,16384)      : x fp32 -> bf16 (4 elems/thread)
// blocks [16384,20480)  : VWt + OWt transposes (1M elems)
// blocks [20480,20736)  : Ktp build (64K elems)
// blocks [20736,20992)  : p1 / p2e sinusoid tables
__global__ __launch_bounds__(256) void prep_all(
    const float* __restrict__ x,
    const float* __restrict__ k1, const float* __restrict__ k2, const float* __restrict__ k3,
    const float* __restrict__ a1, const float* __restrict__ a2,
    const float* __restrict__ b1, const float* __restrict__ b2, const float* __restrict__ c,
    const float* __restrict__ vw, const float* __restrict__ ow,
    bf16* __restrict__ xb, bf16* __restrict__ Ktp,
    bf16* __restrict__ VWt, bf16* __restrict__ OWt,
    float* __restrict__ p1, float* __restrict__ p2e){
    const int blk = blockIdx.x, tid = threadIdx.x;
    if (blk < 16384){
        size_t i = ((size_t)blk * 256 + tid) * 4;
        float4 v = *(const float4*)(x + i);
        bf16 t0 = __float2bfloat16(v.x), t1 = __float2bfloat16(v.y);
        bf16 t2 = __float2bfloat16(v.z), t3 = __float2bfloat16(v.w);
        ushort4 pk = make_ushort4(*(unsigned short*)&t0, *(unsigned short*)&t1,
                                  *(unsigned short*)&t2, *(unsigned short*)&t3);
        *(ushort4*)(xb + i) = pk;
    } else if (blk < 20480){
        int idx = (blk - 16384) * 256 + tid;        // 0..1M
        {   // VWt[r*1024 + w] = vw[h,w,a], r = h*64+a
            int r = idx >> 10, w = idx & 1023;
            int h = r >> 6, a = r & 63;
            VWt[idx] = __float2bfloat16(vw[(h << 16) + (w << 6) + a]);
        }
        {   // OWt[w*1024 + r] = ow[h,w,a]
            int w = idx >> 10, r = idx & 1023;
            int h = r >> 6, a = r & 63;
            OWt[idx] = __float2bfloat16(ow[(h << 16) + (w << 6) + a]);
        }
    } else if (blk < 20736){
        int idx = (blk - 20480) * 256 + tid;        // r*1024 + k
        int r = idx >> 10, k = idx & 1023;
        float v = 0.f;
        if (r < 16)      v = k1[r * 1024 + k];
        else if (r < 32) v = k2[(r - 16) * 1024 + k];
        else if (r < 48) v = k3[(r - 32) * 1024 + k];
        Ktp[idx] = __float2bfloat16(v);
    } else {
        int idx = (blk - 20736) * 256 + tid;        // h*N + i
        int h = idx >> 12, i = idx & (Nn - 1);
        float t = (float)i * (1.0f / (float)(Nn - 1));
        float s1 = 0.f, s2 = 0.f;
        for (int p = 0; p < Pp; ++p){
            float av1 = a1[h * Pp + p], av2 = a2[h * Pp + p];
            float bv1 = b1[h * Pp + p], bv2 = b2[h * Pp + p];
            float cv  = c [h * Pp + p];
            s1 += __sinf(av1 * t + bv1) * cv;
            s2 += __sinf(av2 * t + bv2) * cv;
        }
        p1[idx]  = s1;
        p2e[idx] = expf(clamp20(s2));
    }
}

// ---- projection GEMM: S[16384,48] = xb * Ktp^T, epilogue exp+scatter -----
__global__ __launch_bounds__(256) void proj_gemm(const bf16* __restrict__ A,
                                                 const bf16* __restrict__ Ktp,
                                                 const float* __restrict__ p1,
                                                 float* __restrict__ cross_e,
                                                 float* __restrict__ diag_e,
                                                 float* __restrict__ extra_e){
    __shared__ bf16 As[256 * 32];
    __shared__ bf16 Bs[64 * 32];
    const int tid  = threadIdx.x;
    const int wave = tid >> 6, lane = tid & 63;
    const int m0 = blockIdx.x * 256;

    const int lrow = lane >> 2;            // 0..15
    const int scol = (lane & 3) * 8;       // 0,8,16,24
    const bf16* Bg = Ktp + (size_t)(wave * 16 + lrow) * 1024 + scol;
    bf16* Bl = Bs + (wave * 16) * 32;

    floatx4 acc[4][3] = {};
    const int fr = lane & 15;
    const int fk = (lane >> 4) * 8;

    for (int k0 = 0; k0 < 1024; k0 += 32){
#pragma unroll
        for (int q = 0; q < 4; ++q){
            int srow = wave * 64 + q * 16 + lrow;
            gl_lds16(A + (size_t)(m0 + srow) * 1024 + k0 + scol, As + (wave * 64 + q * 16) * 32);
        }
        gl_lds16(Bg + k0, Bl);
        __syncthreads();
        short8 af[4], bfr[3];
#pragma unroll
        for (int i = 0; i < 4; ++i)
            af[i] = *(const short8*)&As[(wave * 64 + i * 16 + fr) * 32 + fk];
#pragma unroll
        for (int j = 0; j < 3; ++j)
            bfr[j] = *(const short8*)&Bs[(j * 16 + fr) * 32 + fk];
#pragma unroll
        for (int i = 0; i < 4; ++i)
#pragma unroll
            for (int j = 0; j < 3; ++j)
                acc[i][j] = __builtin_amdgcn_mfma_f32_16x16x32_bf16(af[i], bfr[j], acc[i][j], 0, 0, 0);
        __syncthreads();
    }

    const int cr = (lane >> 4) * 4;
#pragma unroll
    for (int i = 0; i < 4; ++i){
#pragma unroll
        for (int j = 0; j < 3; ++j){
            float* dst = (j == 0) ? cross_e : (j == 1) ? diag_e : extra_e;
#pragma unroll
            for (int r = 0; r < 4; ++r){
                int row = m0 + wave * 64 + i * 16 + cr + r;
                int n = row & (Nn - 1), b = row >> 12;
                float s = acc[i][j][r];
                if (j == 0) s += p1[fr * Nn + n];
                dst[(b * Hh + fr) * Nn + n] = expf(clamp20(s));
            }
        }
    }
}

// ---- MFMA GEMM, BK=64, XOR-swizzled LDS: C[M,N] = A[M,K]*Bt[N,K]^T -------
template<int WRITE_BF16>
__global__ __launch_bounds__(256) void gemm_bt(const bf16* __restrict__ A,
                                               const bf16* __restrict__ Bt,
                                               void* __restrict__ Cv,
                                               int M, int N, int K){
    __shared__ bf16 As[128 * 64];
    __shared__ bf16 Bs[128 * 64];
    const int tid  = threadIdx.x;
    const int wave = tid >> 6, lane = tid & 63;
    const int m0 = blockIdx.y * 128, n0 = blockIdx.x * 128;
    const int wm = (wave & 1) * 64, wn = (wave >> 1) * 64;

    const int lrow = lane >> 3;                          // 0..7
    const int lcol = ((lane & 7) ^ lrow) * 8;            // swizzled source col
    const bf16* Ag = A  + (size_t)(m0 + wave * 32 + lrow) * K + lcol;
    const bf16* Bg = Bt + (size_t)(n0 + wave * 32 + lrow) * K + lcol;
    bf16* Al = As + (wave * 32) * 64;
    bf16* Bl = Bs + (wave * 32) * 64;

    floatx4 acc[4][4] = {};
    const int fr = lane & 15;
    const int quad = lane >> 4;

    for (int k0 = 0; k0 < K; k0 += 64){
#pragma unroll
        for (int q = 0; q < 4; ++q){
            gl_lds16(Ag + k0 + (size_t)(q * 8) * K, Al + q * 8 * 64);
            gl_lds16(Bg + k0 + (size_t)(q * 8) * K, Bl + q * 8 * 64);
        }
        __syncthreads();
#pragma unroll
        for (int kk = 0; kk < 64; kk += 32){
            const int lbase = (kk >> 3) + quad;          // logical 8-elem chunk
            short8 af[4], bfr[4];
#pragma unroll
            for (int i = 0; i < 4; ++i){
                int R = wm + i * 16 + fr;
                af[i] = *(const short8*)&As[R * 64 + ((lbase ^ (R & 7)) << 3)];
            }
#pragma unroll
            for (int j = 0; j < 4; ++j){
                int R = wn + j * 16 + fr;
                bfr[j] = *(const short8*)&Bs[R * 64 + ((lbase ^ (R & 7)) << 3)];
            }
#pragma unroll
            for (int i = 0; i < 4; ++i)
#pragma unroll
                for (int j = 0; j < 4; ++j)
                    acc[i][j] = __builtin_amdgcn_mfma_f32_16x16x32_bf16(af[i], bfr[j], acc[i][j], 0, 0, 0);
        }
        __syncthreads();
    }

    const int cr = quad * 4;
#pragma unroll
    for (int i = 0; i < 4; ++i)
#pragma unroll
        for (int j = 0; j < 4; ++j){
            int row = m0 + wm + i * 16 + cr;
            int col = n0 + wn + j * 16 + fr;
            if (WRITE_BF16){
                bf16* C = (bf16*)Cv;
#pragma unroll
                for (int r = 0; r < 4; ++r)
                    C[(size_t)(row + r) * N + col] = __float2bfloat16(acc[i][j][r]);
            } else {
                float* C = (float*)Cv;
#pragma unroll
                for (int r = 0; r < 4; ++r)
                    C[(size_t)(row + r) * N + col] = acc[i][j][r];
            }
        }
}

// ---- scan pass 1: per-chunk sums ----------------------------------------
__global__ __launch_bounds__(64) void scan1(const bf16* __restrict__ values,
                                            const float* __restrict__ cross_e,
                                            float* __restrict__ csum_c, float* __restrict__ csum_cv){
    const int blk = blockIdx.x;          // (b*H + h)*J + j
    const int j = blk & (Jj - 1);
    const int bh = blk >> 6;
    const int h = bh & (Hh - 1), b = bh >> 4;
    const int lane = threadIdx.x;
    const float* cp = cross_e + bh * Nn + j * Ll;
    float sc = 0.f, scv = 0.f;
    for (int t = 0; t < Ll; ++t){
        int n = j * Ll + t;
        float ce = cp[t];
        float v = __bfloat162float(values[((size_t)(b * Nn + n) << 10) + (h << 6) + lane]);
        sc += ce;
        scv += ce * v;
    }
    if (lane == 0) csum_c[blk] = sc;
    csum_cv[(blk << 6) + lane] = scv;
}

// ---- scan pass 2: exclusive prefix over chunks ---------------------------
__global__ __launch_bounds__(64) void scan2(const float* __restrict__ csum_c,
                                            const float* __restrict__ csum_cv,
                                            float* __restrict__ pref_c, float* __restrict__ pref_cv){
    const int bh = blockIdx.x;
    const int lane = threadIdx.x;
    float rc = 0.f, rcv = 0.f;
    for (int j = 0; j < Jj; ++j){
        int idx = bh * Jj + j;
        if (lane == 0) pref_c[idx] = rc;
        pref_cv[(idx << 6) + lane] = rcv;
        rc  += csum_c[idx];
        rcv += csum_cv[(idx << 6) + lane];
    }
}

// ---- scan pass 3: apply + pointwise -> out2 bf16 [B][N][H*A] -------------
__global__ __launch_bounds__(64) void scan3(const bf16* __restrict__ values,
                                            const float* __restrict__ cross_e,
                                            const float* __restrict__ diag_e,
                                            const float* __restrict__ extra_e,
                                            const float* __restrict__ p2e,
                                            const float* __restrict__ pref_c,
                                            const float* __restrict__ pref_cv,
                                            bf16* __restrict__ out2){
    const int blk = blockIdx.x;
    const int j = blk & (Jj - 1);
    const int bh = blk >> 6;
    const int h = bh & (Hh - 1), b = bh >> 4;
    const int lane = threadIdx.x;
    const float* cp = cross_e + bh * Nn + j * Ll;
    const float* dp = diag_e  + bh * Nn + j * Ll;
    const float* ep = extra_e + bh * Nn + j * Ll;
    const float* pp = p2e + h * Nn + j * Ll;
    float rc  = pref_c[blk];
    float rcv = pref_cv[(blk << 6) + lane];
    for (int t = 0; t < Ll; ++t){
        int n = j * Ll + t;
        float ce = cp[t], de = dp[t], ee = ep[t], pe = pp[t];
        size_t vidx = ((size_t)(b * Nn + n) << 10) + (h << 6) + lane;
        float v = __bfloat162float(values[vidx]);
        rcv += ce * v;
        rc  += ce;
        float pee = pe * ee;
        float num = rcv * pee + v * de;
        float den = rc  * pee + de;
        out2[vidx] = __float2bfloat16(num / den);
    }
}

extern "C" void kernel_launch(void* const* d_in, const int* in_sizes, int n_in,
                              void* d_out, int out_size, void* d_ws, size_t ws_size,
                              hipStream_t stream){
    const float* x  = (const float*)d_in[0];
    const float* k1 = (const float*)d_in[1];
    const float* k2 = (const float*)d_in[2];
    const float* k3 = (const float*)d_in[3];
    const float* a1 = (const float*)d_in[4];
    const float* a2 = (const float*)d_in[5];
    const float* b1 = (const float*)d_in[6];
    const float* b2 = (const float*)d_in[7];
    const float* c  = (const float*)d_in[8];
    const float* vw = (const float*)d_in[9];
    const float* ow = (const float*)d_in[10];
    float* out = (float*)d_out;

    char* p = (char*)d_ws;
    auto alloc = [&](size_t bytes) -> void* {
        void* r = (void*)p;
        p += (bytes + 255) & ~(size_t)255;
        return r;
    };
    bf16*  xb      = (bf16*) alloc((size_t)Bb * Nn * Ww * 2);
    bf16*  Ktp     = (bf16*) alloc((size_t)64 * Ww * 2);
    bf16*  VWt     = (bf16*) alloc((size_t)Hh * Aa * Ww * 2);
    bf16*  OWt     = (bf16*) alloc((size_t)Ww * Hh * Aa * 2);
    float* p1      = (float*)alloc((size_t)Hh * Nn * 4);
    float* p2e     = (float*)alloc((size_t)Hh * Nn * 4);
    float* cross_e = (float*)alloc((size_t)Bb * Hh * Nn * 4);
    float* diag_e  = (float*)alloc((size_t)Bb * Hh * Nn * 4);
    float* extra_e = (float*)alloc((size_t)Bb * Hh * Nn * 4);
    float* csum_c  = (float*)alloc((size_t)Bb * Hh * Jj * 4);
    float* pref_c  = (float*)alloc((size_t)Bb * Hh * Jj * 4);
    float* csum_cv = (float*)alloc((size_t)Bb * Hh * Jj * Aa * 4);
    float* pref_cv = (float*)alloc((size_t)Bb * Hh * Jj * Aa * 4);
    bf16*  values  = (bf16*) alloc((size_t)Bb * Nn * Hh * Aa * 2);
    bf16*  out2    = (bf16*) alloc((size_t)Bb * Nn * Hh * Aa * 2);

    prep_all<<<20992, 256, 0, stream>>>(x, k1, k2, k3, a1, a2, b1, b2, c, vw, ow,
                                        xb, Ktp, VWt, OWt, p1, p2e);
    proj_gemm<<<(Bb * Nn) / 256, 256, 0, stream>>>(xb, Ktp, p1, cross_e, diag_e, extra_e);
    gemm_bt<1><<<dim3((Hh * Aa) / 128, (Bb * Nn) / 128), 256, 0, stream>>>(xb, VWt, (void*)values, Bb * Nn, Hh * Aa, Ww);
    scan1<<<Bb * Hh * Jj, 64, 0, stream>>>(values, cross_e, csum_c, csum_cv);
    scan2<<<Bb * Hh, 64, 0, stream>>>(csum_c, csum_cv, pref_c, pref_cv);
    scan3<<<Bb * Hh * Jj, 64, 0, stream>>>(values, cross_e, diag_e, extra_e, p2e, pref_c, pref_cv, out2);
    gemm_bt<0><<<dim3(Ww / 128, (Bb * Nn) / 128), 256, 0, stream>>>(out2, OWt, (void*)out, Bb * Nn, Ww, Hh * Aa);
}